// Round 10
// baseline (149.987 us; speedup 1.0000x reference)
//
#include <hip/hip_runtime.h>
#include <math.h>
#include <stdint.h>

#define B_   4
#define N_   2048
#define D_   512
#define DK_  512
#define NH_  8
#define HK_  64
#define LN_EPS_ 1e-5f
// softmax runs in exp2 domain: Q is pre-scaled by 1/sqrt(64) * log2(e)
#define QS_  0.18033688011112042f

typedef unsigned short u16;
typedef __attribute__((ext_vector_type(8))) short short8;
typedef __attribute__((ext_vector_type(4))) float f32x4;
typedef __attribute__((ext_vector_type(8))) unsigned short u16x8;

__device__ __forceinline__ u16 f2bf(float x) {          // RNE
    uint32_t u = __builtin_bit_cast(uint32_t, x);
    return (u16)((u + 0x7fffu + ((u >> 16) & 1u)) >> 16);
}
__device__ __forceinline__ u16 f2bf_fast(float x) {     // round-half-up (2 ops)
    return (u16)((__builtin_bit_cast(uint32_t, x) + 0x8000u) >> 16);
}
__device__ __forceinline__ float exp2f_fast(float x) {
    return __builtin_amdgcn_exp2f(x);
}

// async global->LDS, 16B/lane; LDS dest = wave-uniform base + lane*16
__device__ __forceinline__ void gload16(const void* g, void* l) {
    __builtin_amdgcn_global_load_lds(
        reinterpret_cast<const __attribute__((address_space(1))) void*>(
            reinterpret_cast<uintptr_t>(g)),
        reinterpret_cast<__attribute__((address_space(3))) void*>(
            static_cast<uint32_t>(reinterpret_cast<uintptr_t>(l))),
        16, 0, 0);
}

// ---------------------------------------------------------------------------
__global__ __launch_bounds__(256) void conv_bf16_kernel(
    const float* __restrict__ src, u16* __restrict__ dst, int n)
{
    const int i = (blockIdx.x * 256 + threadIdx.x) * 8;
    if (i >= n) return;
    const float4 a = *reinterpret_cast<const float4*>(&src[i]);
    const float4 b = *reinterpret_cast<const float4*>(&src[i + 4]);
    u16x8 o;
    o[0] = f2bf(a.x); o[1] = f2bf(a.y); o[2] = f2bf(a.z); o[3] = f2bf(a.w);
    o[4] = f2bf(b.x); o[5] = f2bf(b.y); o[6] = f2bf(b.z); o[7] = f2bf(b.w);
    *reinterpret_cast<u16x8*>(&dst[i]) = o;
}

// three 512x512 W[K][Nc] fp32 -> Wt[Nc][K] bf16, z selects the matrix
__global__ __launch_bounds__(256) void tc3_kernel(
    const float* __restrict__ W0, const float* __restrict__ W1,
    const float* __restrict__ W2, u16* __restrict__ Wt)
{
    __shared__ float t[32][33];
    const float* W = blockIdx.z == 0 ? W0 : (blockIdx.z == 1 ? W1 : W2);
    u16* dst = Wt + (size_t)blockIdx.z * 512 * 512;
    const int tid = threadIdx.x;
    const int kt = blockIdx.y * 32, nt = blockIdx.x * 32;
    {
        const int r = tid >> 3, c0 = (tid & 7) * 4;
        const float4 v = *reinterpret_cast<const float4*>(
            &W[(size_t)(kt + r) * 512 + nt + c0]);
        t[r][c0] = v.x; t[r][c0 + 1] = v.y; t[r][c0 + 2] = v.z; t[r][c0 + 3] = v.w;
    }
    __syncthreads();
    {
        const int nidx = tid >> 3, kc = (tid & 7) * 4;
        u16 o[4];
        #pragma unroll
        for (int j = 0; j < 4; ++j) o[j] = f2bf(t[kc + j][nidx]);
        *reinterpret_cast<ushort4*>(&dst[(size_t)(nt + nidx) * 512 + kt + kc]) =
            make_ushort4(o[0], o[1], o[2], o[3]);
    }
}

// Wf[1024][512] fp32 -> WfT[512][1024] bf16
__global__ __launch_bounds__(256) void tcf_kernel(
    const float* __restrict__ W, u16* __restrict__ Wt)
{
    __shared__ float t[32][33];
    const int tid = threadIdx.x;
    const int kt = blockIdx.y * 32, nt = blockIdx.x * 32;
    {
        const int r = tid >> 3, c0 = (tid & 7) * 4;
        const float4 v = *reinterpret_cast<const float4*>(
            &W[(size_t)(kt + r) * 512 + nt + c0]);
        t[r][c0] = v.x; t[r][c0 + 1] = v.y; t[r][c0 + 2] = v.z; t[r][c0 + 3] = v.w;
    }
    __syncthreads();
    {
        const int nidx = tid >> 3, kc = (tid & 7) * 4;
        u16 o[4];
        #pragma unroll
        for (int j = 0; j < 4; ++j) o[j] = f2bf(t[kc + j][nidx]);
        *reinterpret_cast<ushort4*>(&Wt[(size_t)(nt + nidx) * 1024 + kt + kc]) =
            make_ushort4(o[0], o[1], o[2], o[3]);
    }
}

// ---------------------------------------------------------------------------
// bf16 MFMA GEMM, tile BM x BN, BK=64, 4 waves (2x2). XCD-swizzled 1-D grid.
// MODE 1: QKV split epilogue (q scaled by QS_; v dual-written to vb and
//         per-head-transposed vt)
// MODE 2: fp32 out + bias + relu + resid
// ---------------------------------------------------------------------------
template<int BM, int BN, int MODE>
__global__ __launch_bounds__(256) void gemm_bf16(
    const u16* __restrict__ A, const u16* __restrict__ Bt,
    float* __restrict__ Cf, u16* __restrict__ qb, u16* __restrict__ kb,
    u16* __restrict__ vb, u16* __restrict__ vt, int M, int Nc, int K,
    const float* __restrict__ bias, const float* __restrict__ resid)
{
    constexpr int MI = BM / 32, NI = BN / 32;
    constexpr int AL = BM / 32, BL = BN / 32;   // 1KB staging chunks per wave
    __shared__ u16 As[BM * 64];
    __shared__ u16 Bs[BN * 64];
    const int tid = threadIdx.x;
    const int lane = tid & 63, wave = tid >> 6;
    const int wm = wave >> 1, wn = wave & 1;
    const int l15 = lane & 15, lg = lane >> 4;

    const int nwg = gridDim.x;
    const int bid = ((int)blockIdx.x & 7) * (nwg >> 3) + ((int)blockIdx.x >> 3);
    const int ntiles = Nc / BN;
    const int nt = (bid % ntiles) * BN;
    const int mt = (bid / ntiles) * BM;

    f32x4 acc[MI][NI] = {};

    for (int kt = 0; kt < K; kt += 64) {
        __syncthreads();
        #pragma unroll
        for (int i = 0; i < AL; ++i) {
            const int ob = (wave * AL + i) * 1024;
            const int o = ob + lane * 16;
            const int row = o >> 7;
            const int inner = (o & 127) ^ ((row & 7) << 4);
            gload16((const char*)A + ((size_t)(mt + row) * K + kt) * 2 + inner,
                    (char*)As + ob);
        }
        #pragma unroll
        for (int i = 0; i < BL; ++i) {
            const int ob = (wave * BL + i) * 1024;
            const int o = ob + lane * 16;
            const int row = o >> 7;
            const int inner = (o & 127) ^ ((row & 7) << 4);
            gload16((const char*)Bt + ((size_t)(nt + row) * K + kt) * 2 + inner,
                    (char*)Bs + ob);
        }
        __syncthreads();
        #pragma unroll
        for (int ks = 0; ks < 2; ++ks) {
            const int kb2 = ks * 32 + lg * 8;
            short8 af[MI], bfr[NI];
            #pragma unroll
            for (int mi = 0; mi < MI; ++mi) {
                const int r = wm * (BM / 2) + mi * 16 + l15;
                af[mi] = *reinterpret_cast<const short8*>(
                    &As[r * 64 + (kb2 ^ ((r & 7) << 3))]);
            }
            #pragma unroll
            for (int ni = 0; ni < NI; ++ni) {
                const int r = wn * (BN / 2) + ni * 16 + l15;
                bfr[ni] = *reinterpret_cast<const short8*>(
                    &Bs[r * 64 + (kb2 ^ ((r & 7) << 3))]);
            }
            #pragma unroll
            for (int mi = 0; mi < MI; ++mi)
                #pragma unroll
                for (int ni = 0; ni < NI; ++ni)
                    acc[mi][ni] = __builtin_amdgcn_mfma_f32_16x16x32_bf16(
                        af[mi], bfr[ni], acc[mi][ni], 0, 0, 0);
        }
    }

    #pragma unroll
    for (int mi = 0; mi < MI; ++mi) {
        #pragma unroll
        for (int ni = 0; ni < NI; ++ni) {
            const int col = nt + wn * (BN / 2) + ni * 16 + l15;
            const int row0 = mt + wm * (BM / 2) + mi * 16 + lg * 4;
            if (MODE == 1) {
                if (col < 512) {
                    #pragma unroll
                    for (int jj = 0; jj < 4; ++jj)
                        qb[(size_t)(row0 + jj) * 512 + col] =
                            f2bf(acc[mi][ni][jj] * QS_);
                } else if (col < 1024) {
                    #pragma unroll
                    for (int jj = 0; jj < 4; ++jj)
                        kb[(size_t)(row0 + jj) * 512 + col - 512] =
                            f2bf(acc[mi][ni][jj]);
                } else {
                    const int dfull = col - 1024;
                    const int hh = dfull >> 6, dd = dfull & 63;
                    const int bb = row0 >> 11, nn = row0 & 2047;
                    u16 o4[4];
                    #pragma unroll
                    for (int jj = 0; jj < 4; ++jj) {
                        o4[jj] = f2bf(acc[mi][ni][jj]);
                        vb[(size_t)(row0 + jj) * 512 + dfull] = o4[jj];
                    }
                    *reinterpret_cast<ushort4*>(
                        &vt[(((size_t)(bb * NH_ + hh)) * HK_ + dd) * N_ + nn]) =
                        make_ushort4(o4[0], o4[1], o4[2], o4[3]);
                }
            } else {
                #pragma unroll
                for (int jj = 0; jj < 4; ++jj) {
                    const size_t row = (size_t)(row0 + jj);
                    float v = acc[mi][ni][jj];
                    v += bias[col];
                    v = fmaxf(v, 0.0f);
                    v += resid[row * Nc + col];
                    Cf[row * Nc + col] = v;
                }
            }
        }
    }
}

// ---------------------------------------------------------------------------
// Flash attention, bf16 MFMA, QBLK=128 (R9-proven compute body), now with the
// T3-lite 2-phase schedule: STAGE(next tile -> STATIC other buffer), COMPUTE
// (current buffer), ONE barrier per iter (drains the prefetch after compute
// covered its latency). Static unroll-2 with named buffers Ks0/Ks1/Vs0/Vs1
// (R4's regression was runtime-indexed Ks[cur] -> conservative early wait).
// ---------------------------------------------------------------------------
__global__ __launch_bounds__(256) void flash_bf16_kernel(
    const u16* __restrict__ Qb, const u16* __restrict__ Kb,
    const u16* __restrict__ Vt, u16* __restrict__ att)
{
    __shared__ u16 Ks0[64 * 64];   // [key][d], XOR-swizzled rows
    __shared__ u16 Ks1[64 * 64];
    __shared__ u16 Vs0[64 * 64];   // [d][key], XOR-swizzled rows
    __shared__ u16 Vs1[64 * 64];
    __shared__ u16 Ps[128 * 64];   // [q][key], XOR-swizzled rows
    const int tid = threadIdx.x;
    const int lane = tid & 63, wave = tid >> 6;
    const int l15 = lane & 15, lg = lane >> 4;
    // grid 512, XCD swizzle (64 blocks per XCD chunk)
    const int lbid = (((int)blockIdx.x & 7) << 6) + ((int)blockIdx.x >> 3);
    const int qt = lbid & 15, h = (lbid >> 4) & 7, b = lbid >> 7;

    short8 aq[2][2];
    #pragma unroll
    for (int qs = 0; qs < 2; ++qs) {
        const int qrow = qt * 128 + qs * 64 + wave * 16 + l15;
        const u16* qp = Qb + ((size_t)(b * N_ + qrow)) * DK_ + h * HK_ + lg * 8;
        aq[qs][0] = *reinterpret_cast<const short8*>(qp);
        aq[qs][1] = *reinterpret_cast<const short8*>(qp + 32);
    }
    short8 ones;
    #pragma unroll
    for (int i = 0; i < 8; ++i) ones[i] = (short)0x3F80;   // bf16 1.0

    const u16* Kbase = Kb + (size_t)b * N_ * DK_ + (size_t)h * HK_;
    const u16* Vbase = Vt + ((size_t)(b * NH_ + h)) * HK_ * N_;

    f32x4 o[2][5] = {};   // o[qs][4] = row-sum accumulator (l), via ones-MFMA
    float m_[2][4];
    #pragma unroll
    for (int qs = 0; qs < 2; ++qs)
        #pragma unroll
        for (int j = 0; j < 4; ++j) m_[qs][j] = -1e30f;

#define STAGE(ktile, KBUF, VBUF) do {                                          \
    _Pragma("unroll")                                                          \
    for (int i_ = 0; i_ < 2; ++i_) {                                           \
        const int ob_ = (wave * 2 + i_) * 1024;                                \
        const int oo_ = ob_ + lane * 16;                                       \
        const int row_ = oo_ >> 7;                                             \
        const int inner_ = (oo_ & 127) ^ ((row_ & 7) << 4);                    \
        gload16((const char*)Kbase +                                           \
                    ((size_t)((ktile) * 64 + row_) * DK_) * 2 + inner_,        \
                (char*)(KBUF) + ob_);                                          \
        gload16((const char*)Vbase +                                           \
                    ((size_t)row_ * N_ + (ktile) * 64) * 2 + inner_,           \
                (char*)(VBUF) + ob_);                                          \
    }                                                                          \
} while (0)

#define FLASH_STEP(KBUF, VBUF) do {                                            \
    f32x4 s[2][4] = {};                                                        \
    __builtin_amdgcn_s_setprio(1);                                             \
    _Pragma("unroll")                                                          \
    for (int ks = 0; ks < 2; ++ks) {                                           \
        const int kb2 = ks * 32 + lg * 8;                                      \
        _Pragma("unroll")                                                      \
        for (int t = 0; t < 4; ++t) {                                          \
            const int r = t * 16 + l15;                                        \
            const short8 bk = *reinterpret_cast<const short8*>(                \
                &(KBUF)[r * 64 + (kb2 ^ ((r & 7) << 3))]);                     \
            s[0][t] = __builtin_amdgcn_mfma_f32_16x16x32_bf16(                 \
                aq[0][ks], bk, s[0][t], 0, 0, 0);                              \
            s[1][t] = __builtin_amdgcn_mfma_f32_16x16x32_bf16(                 \
                aq[1][ks], bk, s[1][t], 0, 0, 0);                              \
        }                                                                      \
    }                                                                          \
    __builtin_amdgcn_s_setprio(0);                                             \
    float rmax[2][4], cm = -1e30f;                                             \
    _Pragma("unroll")                                                          \
    for (int qs = 0; qs < 2; ++qs)                                             \
        _Pragma("unroll")                                                      \
        for (int jj = 0; jj < 4; ++jj) {                                       \
            rmax[qs][jj] = fmaxf(fmaxf(s[qs][0][jj], s[qs][1][jj]),            \
                                 fmaxf(s[qs][2][jj], s[qs][3][jj]));           \
            cm = fmaxf(cm, rmax[qs][jj] - m_[qs][jj]);                         \
        }                                                                      \
    if (__any(cm > 8.0f)) {                                                    \
        _Pragma("unroll")                                                      \
        for (int qs = 0; qs < 2; ++qs)                                         \
            _Pragma("unroll")                                                  \
            for (int jj = 0; jj < 4; ++jj) {                                   \
                float rm = rmax[qs][jj];                                       \
                rm = fmaxf(rm, __shfl_xor(rm, 1));                             \
                rm = fmaxf(rm, __shfl_xor(rm, 2));                             \
                rm = fmaxf(rm, __shfl_xor(rm, 4));                             \
                rm = fmaxf(rm, __shfl_xor(rm, 8));                             \
                const float newm = fmaxf(m_[qs][jj], rm);                      \
                const float fac = exp2f_fast(m_[qs][jj] - newm);               \
                m_[qs][jj] = newm;                                             \
                _Pragma("unroll")                                              \
                for (int t = 0; t < 5; ++t) o[qs][t][jj] *= fac;               \
            }                                                                  \
    }                                                                          \
    _Pragma("unroll")                                                          \
    for (int qs = 0; qs < 2; ++qs)                                             \
        _Pragma("unroll")                                                      \
        for (int jj = 0; jj < 4; ++jj) {                                       \
            const float p0 = exp2f_fast(s[qs][0][jj] - m_[qs][jj]);            \
            const float p1 = exp2f_fast(s[qs][1][jj] - m_[qs][jj]);            \
            const float p2 = exp2f_fast(s[qs][2][jj] - m_[qs][jj]);            \
            const float p3 = exp2f_fast(s[qs][3][jj] - m_[qs][jj]);            \
            const int prow = qs * 64 + wave * 16 + lg * 4 + jj;                \
            const int pb = prow * 64, sw = (prow & 7) << 3;                    \
            Ps[pb + ((l15     ) ^ sw)] = f2bf_fast(p0);                        \
            Ps[pb + ((l15 + 16) ^ sw)] = f2bf_fast(p1);                        \
            Ps[pb + ((l15 + 32) ^ sw)] = f2bf_fast(p2);                        \
            Ps[pb + ((l15 + 48) ^ sw)] = f2bf_fast(p3);                        \
        }                                                                      \
    __builtin_amdgcn_s_setprio(1);                                             \
    _Pragma("unroll")                                                          \
    for (int ks = 0; ks < 2; ++ks) {                                           \
        const int kb2 = ks * 32 + lg * 8;                                      \
        const int pr0 = wave * 16 + l15;                                       \
        const int pr1 = 64 + pr0;                                              \
        const short8 ap0 = *reinterpret_cast<const short8*>(                   \
            &Ps[pr0 * 64 + (kb2 ^ ((pr0 & 7) << 3))]);                         \
        const short8 ap1 = *reinterpret_cast<const short8*>(                   \
            &Ps[pr1 * 64 + (kb2 ^ ((pr1 & 7) << 3))]);                         \
        _Pragma("unroll")                                                      \
        for (int t = 0; t < 4; ++t) {                                          \
            const int dr = t * 16 + l15;                                       \
            const short8 bv = *reinterpret_cast<const short8*>(                \
                &(VBUF)[dr * 64 + (kb2 ^ ((dr & 7) << 3))]);                   \
            o[0][t] = __builtin_amdgcn_mfma_f32_16x16x32_bf16(                 \
                ap0, bv, o[0][t], 0, 0, 0);                                    \
            o[1][t] = __builtin_amdgcn_mfma_f32_16x16x32_bf16(                 \
                ap1, bv, o[1][t], 0, 0, 0);                                    \
        }                                                                      \
        o[0][4] = __builtin_amdgcn_mfma_f32_16x16x32_bf16(                     \
            ap0, ones, o[0][4], 0, 0, 0);                                      \
        o[1][4] = __builtin_amdgcn_mfma_f32_16x16x32_bf16(                     \
            ap1, ones, o[1][4], 0, 0, 0);                                      \
    }                                                                          \
    __builtin_amdgcn_s_setprio(0);                                             \
} while (0)

    STAGE(0, Ks0, Vs0);
    __syncthreads();   // buf0 ready

    #pragma unroll 1
    for (int kt = 0; kt < N_ / 64; kt += 2) {
        STAGE(kt + 1, Ks1, Vs1);                       // kt+1 <= 31 always
        FLASH_STEP(Ks0, Vs0);
        __syncthreads();                               // drains prefetch; buf1 ready
        if (kt + 2 < N_ / 64) STAGE(kt + 2, Ks0, Vs0);
        FLASH_STEP(Ks1, Vs1);
        __syncthreads();
    }
#undef STAGE
#undef FLASH_STEP

    #pragma unroll
    for (int qs = 0; qs < 2; ++qs)
        #pragma unroll
        for (int jj = 0; jj < 4; ++jj) {
            const float inv = 1.0f / o[qs][4][jj];
            const size_t row = (size_t)b * N_ + qt * 128 + qs * 64 + wave * 16 + lg * 4 + jj;
            #pragma unroll
            for (int t = 0; t < 4; ++t)
                att[row * (2 * DK_) + h * HK_ + t * 16 + l15] =
                    f2bf_fast(o[qs][t][jj] * inv);
        }
}

// ---------------------------------------------------------------------------
// Feature branch: S_f[kd,qd] = sum_n K[n,kd] * Qs[n,qd]  (MFMA, split over n)
// partials[split][bh][64][64] fp32
// ---------------------------------------------------------------------------
__global__ __launch_bounds__(256) void featS_mfma(
    const u16* __restrict__ Kb, const u16* __restrict__ Qb,
    float* __restrict__ partials)
{
    __shared__ u16 KsT[64 * 64];   // [kd][n], XOR-swizzled
    __shared__ u16 QsT[64 * 64];   // [qd][n], XOR-swizzled
    const int tid = threadIdx.x;
    const int lane = tid & 63, wave = tid >> 6;
    const int l15 = lane & 15, lg = lane >> 4;
    const int ns = blockIdx.x, h = blockIdx.y, b = blockIdx.z;
    const size_t hbase = (size_t)b * N_ * DK_ + (size_t)h * HK_;

    f32x4 acc[4] = {};
    for (int c = 0; c < 4; ++c) {
        const int n0 = ns * 256 + c * 64;
        __syncthreads();
        #pragma unroll
        for (int it = 0; it < 2; ++it) {
            const int idx = tid + it * 256;
            const int n = idx >> 3, d0 = (idx & 7) * 8;
            const u16x8 kv = *reinterpret_cast<const u16x8*>(
                &Kb[hbase + (size_t)(n0 + n) * DK_ + d0]);
            const u16x8 qv = *reinterpret_cast<const u16x8*>(
                &Qb[hbase + (size_t)(n0 + n) * DK_ + d0]);
            #pragma unroll
            for (int j = 0; j < 8; ++j) {
                const int r = d0 + j;
                const int cidx = n ^ ((r & 7) << 3);
                KsT[r * 64 + cidx] = kv[j];
                QsT[r * 64 + cidx] = qv[j];
            }
        }
        __syncthreads();
        #pragma unroll
        for (int ks = 0; ks < 2; ++ks) {
            const int kb2 = ks * 32 + lg * 8;
            const int ar = wave * 16 + l15;
            const short8 aK = *reinterpret_cast<const short8*>(
                &KsT[ar * 64 + (kb2 ^ ((ar & 7) << 3))]);
            #pragma unroll
            for (int ni = 0; ni < 4; ++ni) {
                const int br = ni * 16 + l15;
                const short8 bQ = *reinterpret_cast<const short8*>(
                    &QsT[br * 64 + (kb2 ^ ((br & 7) << 3))]);
                acc[ni] = __builtin_amdgcn_mfma_f32_16x16x32_bf16(aK, bQ, acc[ni], 0, 0, 0);
            }
        }
    }
    const int bh = b * NH_ + h;
    #pragma unroll
    for (int ni = 0; ni < 4; ++ni)
        #pragma unroll
        for (int jj = 0; jj < 4; ++jj) {
            const int row = wave * 16 + lg * 4 + jj;
            partials[(((size_t)ns * 32 + bh) * 64 + row) * 64 + ni * 16 + l15] =
                acc[ni][jj];
        }
}

// sum partials, softmax over qd, write distfT[bh][qd][kd] bf16
__global__ __launch_bounds__(256) void featSM_kernel(
    const float* __restrict__ partials, u16* __restrict__ distfT)
{
    const int bh = blockIdx.x, tid = threadIdx.x;
    const int r = tid >> 2, qq = tid & 3;   // row kd=r, cols qq*16..+15
    float v[16];
    #pragma unroll
    for (int j = 0; j < 16; ++j) v[j] = 0.0f;
    for (int s = 0; s < 8; ++s) {
        const float4* pp = reinterpret_cast<const float4*>(
            &partials[(((size_t)s * 32 + bh) * 64 + r) * 64 + qq * 16]);
        #pragma unroll
        for (int j4 = 0; j4 < 4; ++j4) {
            const float4 a = pp[j4];
            v[j4 * 4 + 0] += a.x; v[j4 * 4 + 1] += a.y;
            v[j4 * 4 + 2] += a.z; v[j4 * 4 + 3] += a.w;
        }
    }
    float m = v[0];
    #pragma unroll
    for (int j = 1; j < 16; ++j) m = fmaxf(m, v[j]);
    m = fmaxf(m, __shfl_xor(m, 1));
    m = fmaxf(m, __shfl_xor(m, 2));
    float sum = 0.0f;
    #pragma unroll
    for (int j = 0; j < 16; ++j) { v[j] = exp2f_fast(v[j] - m); sum += v[j]; }
    sum += __shfl_xor(sum, 1);
    sum += __shfl_xor(sum, 2);
    const float inv = 1.0f / sum;
    #pragma unroll
    for (int j = 0; j < 16; ++j)
        distfT[(size_t)bh * 4096 + (qq * 16 + j) * 64 + r] = f2bf_fast(v[j] * inv);
}

// att_f[n,q] = sum_d V[n,d] * distf[d,q] -> att[:, 512+h*64+q] (MFMA)
__global__ __launch_bounds__(256) void featAV_mfma(
    const u16* __restrict__ V, const u16* __restrict__ distfT,
    u16* __restrict__ att)
{
    __shared__ u16 Bs[64 * 64];   // distfT[q][d], XOR-swizzled
    __shared__ u16 As[64 * 64];   // V rows
    const int tid = threadIdx.x;
    const int lane = tid & 63, wave = tid >> 6;
    const int l15 = lane & 15, lg = lane >> 4;
    const int ns = blockIdx.x, h = blockIdx.y, b = blockIdx.z;
    const int bh = b * NH_ + h;

    #pragma unroll
    for (int it = 0; it < 2; ++it) {
        const int idx = tid + it * 256;
        const int r = idx >> 3, c0 = (idx & 7) * 8;
        const u16x8 dv = *reinterpret_cast<const u16x8*>(
            &distfT[(size_t)bh * 4096 + r * 64 + c0]);
        *reinterpret_cast<u16x8*>(&Bs[r * 64 + (c0 ^ ((r & 7) << 3))]) = dv;
    }

    for (int c = 0; c < 4; ++c) {
        const int n0 = ns * 256 + c * 64;
        __syncthreads();
        #pragma unroll
        for (int i = 0; i < 2; ++i) {
            const int ob = (wave * 2 + i) * 1024;
            const int o_ = ob + lane * 16;
            const int row = o_ >> 7;
            const int inner = (o_ & 127) ^ ((row & 7) << 4);
            gload16((const char*)V + ((size_t)(b * N_ + n0 + row) * DK_ + h * HK_) * 2 + inner,
                    (char*)As + ob);
        }
        __syncthreads();
        f32x4 acc[4] = {};
        #pragma unroll
        for (int ks = 0; ks < 2; ++ks) {
            const int kb2 = ks * 32 + lg * 8;
            const int ar = wave * 16 + l15;
            const short8 av = *reinterpret_cast<const short8*>(
                &As[ar * 64 + (kb2 ^ ((ar & 7) << 3))]);
            #pragma unroll
            for (int ni = 0; ni < 4; ++ni) {
                const int br = ni * 16 + l15;
                const short8 bd = *reinterpret_cast<const short8*>(
                    &Bs[br * 64 + (kb2 ^ ((br & 7) << 3))]);
                acc[ni] = __builtin_amdgcn_mfma_f32_16x16x32_bf16(av, bd, acc[ni], 0, 0, 0);
            }
        }
        #pragma unroll
        for (int ni = 0; ni < 4; ++ni)
            #pragma unroll
            for (int jj = 0; jj < 4; ++jj)
                att[((size_t)b * N_ + n0 + wave * 16 + lg * 4 + jj) * (2 * DK_)
                    + 512 + h * HK_ + ni * 16 + l15] = f2bf_fast(acc[ni][jj]);
    }
}

// ---------------------------------------------------------------------------
__global__ __launch_bounds__(256) void ln_kernel(
    const float* __restrict__ fc, const float* __restrict__ gamma,
    const float* __restrict__ beta, float* __restrict__ out)
{
    __shared__ float red[8];
    const int row = blockIdx.x, tid = threadIdx.x;
    const int c = tid * 2;
    const float2 v = *reinterpret_cast<const float2*>(&fc[(size_t)row * D_ + c]);
    float s = v.x + v.y;
    float sq = v.x * v.x + v.y * v.y;
    #pragma unroll
    for (int off = 32; off >= 1; off >>= 1) {
        s  += __shfl_xor(s, off);
        sq += __shfl_xor(sq, off);
    }
    const int lane = tid & 63, w = tid >> 6;
    if (lane == 0) { red[w] = s; red[4 + w] = sq; }
    __syncthreads();
    s  = red[0] + red[1] + red[2] + red[3];
    sq = red[4] + red[5] + red[6] + red[7];
    const float mu = s * (1.0f / D_);
    const float var = sq * (1.0f / D_) - mu * mu;
    const float rstd = rsqrtf(var + LN_EPS_);
    float2 o;
    o.x = (v.x - mu) * rstd * gamma[c] + beta[c];
    o.y = (v.y - mu) * rstd * gamma[c + 1] + beta[c + 1];
    *reinterpret_cast<float2*>(&out[(size_t)row * D_ + c]) = o;
}

// ---------------------------------------------------------------------------
extern "C" void kernel_launch(void* const* d_in, const int* in_sizes, int n_in,
                              void* d_out, int out_size, void* d_ws, size_t ws_size,
                              hipStream_t stream)
{
    (void)in_sizes; (void)n_in; (void)out_size; (void)ws_size;
    const float* x     = (const float*)d_in[0];
    const float* Wq    = (const float*)d_in[1];
    const float* Wk    = (const float*)d_in[2];
    const float* Wv    = (const float*)d_in[3];
    const float* Wf    = (const float*)d_in[4];
    const float* bf    = (const float*)d_in[5];
    const float* gamma = (const float*)d_in[6];
    const float* beta  = (const float*)d_in[7];
    float* out = (float*)d_out;

    char* w = (char*)d_ws;
    const size_t SZE = (size_t)B_ * N_ * DK_;            // 4,194,304 elems
    u16* xb     = (u16*)w;   w += SZE * 2;
    u16* wqkvT  = (u16*)w;   w += (size_t)1536 * 512 * 2;
    u16* wfT    = (u16*)w;   w += (size_t)512 * 1024 * 2;
    u16* qb     = (u16*)w;   w += SZE * 2;
    u16* kb     = (u16*)w;   w += SZE * 2;
    u16* vb     = (u16*)w;   w += SZE * 2;
    u16* vt     = (u16*)w;   w += SZE * 2;
    u16* attb   = (u16*)w;   w += SZE * 2 * 2;
    float* partials = (float*)w; w += (size_t)8 * 32 * 4096 * 4;   // 4 MB
    u16* distfT = (u16*)w;   w += (size_t)32 * 4096 * 2;
    float* fcout = (float*)w;

    const dim3 blk(256);
    const int M = B_ * N_;

    conv_bf16_kernel<<<dim3((B_ * N_ * D_) / 2048), blk, 0, stream>>>(x, xb, B_ * N_ * D_);
    tc3_kernel<<<dim3(16, 16, 3), blk, 0, stream>>>(Wq, Wk, Wv, wqkvT);
    tcf_kernel<<<dim3(16, 32), blk, 0, stream>>>(Wf, wfT);

    // fused QKV projection: [8192,512] @ [512,1536]; q pre-scaled; v dual-write
    gemm_bf16<128, 128, 1><<<dim3(768), blk, 0, stream>>>(
        xb, wqkvT, nullptr, qb, kb, vb, vt, M, 1536, 512, nullptr, nullptr);

    // QBLK=128 flash, 2-phase pipelined: grid 512
    flash_bf16_kernel<<<dim3(512), blk, 0, stream>>>(qb, kb, vt, attb);

    featS_mfma<<<dim3(8, NH_, B_), blk, 0, stream>>>(kb, qb, partials);
    featSM_kernel<<<dim3(32), blk, 0, stream>>>(partials, distfT);
    featAV_mfma<<<dim3(8, NH_, B_), blk, 0, stream>>>(vb, distfT, attb);

    // FC + bias + relu + resid (fp32 out), 128x128 tile, grid 256
    gemm_bf16<128, 128, 2><<<dim3(256), blk, 0, stream>>>(
        attb, wfT, fcout, nullptr, nullptr, nullptr, nullptr, M, D_, 2 * DK_, bf, x);

    ln_kernel<<<dim3(M), blk, 0, stream>>>(fcout, gamma, beta, out);
}

// Round 11
// 143.121 us; speedup vs baseline: 1.0480x; 1.0480x over previous
//
#include <hip/hip_runtime.h>
#include <math.h>
#include <stdint.h>

#define B_   4
#define N_   2048
#define D_   512
#define DK_  512
#define NH_  8
#define HK_  64
#define LN_EPS_ 1e-5f
// softmax runs in exp2 domain: Q is pre-scaled by 1/sqrt(64) * log2(e)
#define QS_  0.18033688011112042f

typedef unsigned short u16;
typedef __attribute__((ext_vector_type(8))) short short8;
typedef __attribute__((ext_vector_type(4))) float f32x4;
typedef __attribute__((ext_vector_type(8))) unsigned short u16x8;

__device__ __forceinline__ u16 f2bf(float x) {          // RNE
    uint32_t u = __builtin_bit_cast(uint32_t, x);
    return (u16)((u + 0x7fffu + ((u >> 16) & 1u)) >> 16);
}
__device__ __forceinline__ u16 f2bf_fast(float x) {     // round-half-up (2 ops)
    return (u16)((__builtin_bit_cast(uint32_t, x) + 0x8000u) >> 16);
}
__device__ __forceinline__ uint32_t pack2bf(float a, float b) {
    return (uint32_t)f2bf_fast(a) | ((uint32_t)f2bf_fast(b) << 16);
}
__device__ __forceinline__ float exp2f_fast(float x) {
    return __builtin_amdgcn_exp2f(x);
}

// async global->LDS, 16B/lane; LDS dest = wave-uniform base + lane*16
__device__ __forceinline__ void gload16(const void* g, void* l) {
    __builtin_amdgcn_global_load_lds(
        reinterpret_cast<const __attribute__((address_space(1))) void*>(
            reinterpret_cast<uintptr_t>(g)),
        reinterpret_cast<__attribute__((address_space(3))) void*>(
            static_cast<uint32_t>(reinterpret_cast<uintptr_t>(l))),
        16, 0, 0);
}

// ---------------------------------------------------------------------------
__global__ __launch_bounds__(256) void conv_bf16_kernel(
    const float* __restrict__ src, u16* __restrict__ dst, int n)
{
    const int i = (blockIdx.x * 256 + threadIdx.x) * 8;
    if (i >= n) return;
    const float4 a = *reinterpret_cast<const float4*>(&src[i]);
    const float4 b = *reinterpret_cast<const float4*>(&src[i + 4]);
    u16x8 o;
    o[0] = f2bf(a.x); o[1] = f2bf(a.y); o[2] = f2bf(a.z); o[3] = f2bf(a.w);
    o[4] = f2bf(b.x); o[5] = f2bf(b.y); o[6] = f2bf(b.z); o[7] = f2bf(b.w);
    *reinterpret_cast<u16x8*>(&dst[i]) = o;
}

// three 512x512 W[K][Nc] fp32 -> Wt[Nc][K] bf16, z selects the matrix
__global__ __launch_bounds__(256) void tc3_kernel(
    const float* __restrict__ W0, const float* __restrict__ W1,
    const float* __restrict__ W2, u16* __restrict__ Wt)
{
    __shared__ float t[32][33];
    const float* W = blockIdx.z == 0 ? W0 : (blockIdx.z == 1 ? W1 : W2);
    u16* dst = Wt + (size_t)blockIdx.z * 512 * 512;
    const int tid = threadIdx.x;
    const int kt = blockIdx.y * 32, nt = blockIdx.x * 32;
    {
        const int r = tid >> 3, c0 = (tid & 7) * 4;
        const float4 v = *reinterpret_cast<const float4*>(
            &W[(size_t)(kt + r) * 512 + nt + c0]);
        t[r][c0] = v.x; t[r][c0 + 1] = v.y; t[r][c0 + 2] = v.z; t[r][c0 + 3] = v.w;
    }
    __syncthreads();
    {
        const int nidx = tid >> 3, kc = (tid & 7) * 4;
        u16 o[4];
        #pragma unroll
        for (int j = 0; j < 4; ++j) o[j] = f2bf(t[kc + j][nidx]);
        *reinterpret_cast<ushort4*>(&dst[(size_t)(nt + nidx) * 512 + kt + kc]) =
            make_ushort4(o[0], o[1], o[2], o[3]);
    }
}

// Wf[1024][512] fp32 -> WfT[512][1024] bf16
__global__ __launch_bounds__(256) void tcf_kernel(
    const float* __restrict__ W, u16* __restrict__ Wt)
{
    __shared__ float t[32][33];
    const int tid = threadIdx.x;
    const int kt = blockIdx.y * 32, nt = blockIdx.x * 32;
    {
        const int r = tid >> 3, c0 = (tid & 7) * 4;
        const float4 v = *reinterpret_cast<const float4*>(
            &W[(size_t)(kt + r) * 512 + nt + c0]);
        t[r][c0] = v.x; t[r][c0 + 1] = v.y; t[r][c0 + 2] = v.z; t[r][c0 + 3] = v.w;
    }
    __syncthreads();
    {
        const int nidx = tid >> 3, kc = (tid & 7) * 4;
        u16 o[4];
        #pragma unroll
        for (int j = 0; j < 4; ++j) o[j] = f2bf(t[kc + j][nidx]);
        *reinterpret_cast<ushort4*>(&Wt[(size_t)(nt + nidx) * 1024 + kt + kc]) =
            make_ushort4(o[0], o[1], o[2], o[3]);
    }
}

// ---------------------------------------------------------------------------
// bf16 MFMA GEMM, tile BM x BN, BK=64, 4 waves (2x2). XCD-swizzled 1-D grid.
// MODE 1: QKV split epilogue (q scaled by QS_; v dual-written to vb and
//         per-head-transposed vt)
// MODE 2: fp32 out + bias + relu + resid
// ---------------------------------------------------------------------------
template<int BM, int BN, int MODE>
__global__ __launch_bounds__(256) void gemm_bf16(
    const u16* __restrict__ A, const u16* __restrict__ Bt,
    float* __restrict__ Cf, u16* __restrict__ qb, u16* __restrict__ kb,
    u16* __restrict__ vb, u16* __restrict__ vt, int M, int Nc, int K,
    const float* __restrict__ bias, const float* __restrict__ resid)
{
    constexpr int MI = BM / 32, NI = BN / 32;
    constexpr int AL = BM / 32, BL = BN / 32;   // 1KB staging chunks per wave
    __shared__ u16 As[BM * 64];
    __shared__ u16 Bs[BN * 64];
    const int tid = threadIdx.x;
    const int lane = tid & 63, wave = tid >> 6;
    const int wm = wave >> 1, wn = wave & 1;
    const int l15 = lane & 15, lg = lane >> 4;

    const int nwg = gridDim.x;
    const int bid = ((int)blockIdx.x & 7) * (nwg >> 3) + ((int)blockIdx.x >> 3);
    const int ntiles = Nc / BN;
    const int nt = (bid % ntiles) * BN;
    const int mt = (bid / ntiles) * BM;

    f32x4 acc[MI][NI] = {};

    for (int kt = 0; kt < K; kt += 64) {
        __syncthreads();
        #pragma unroll
        for (int i = 0; i < AL; ++i) {
            const int ob = (wave * AL + i) * 1024;
            const int o = ob + lane * 16;
            const int row = o >> 7;
            const int inner = (o & 127) ^ ((row & 7) << 4);
            gload16((const char*)A + ((size_t)(mt + row) * K + kt) * 2 + inner,
                    (char*)As + ob);
        }
        #pragma unroll
        for (int i = 0; i < BL; ++i) {
            const int ob = (wave * BL + i) * 1024;
            const int o = ob + lane * 16;
            const int row = o >> 7;
            const int inner = (o & 127) ^ ((row & 7) << 4);
            gload16((const char*)Bt + ((size_t)(nt + row) * K + kt) * 2 + inner,
                    (char*)Bs + ob);
        }
        __syncthreads();
        #pragma unroll
        for (int ks = 0; ks < 2; ++ks) {
            const int kb2 = ks * 32 + lg * 8;
            short8 af[MI], bfr[NI];
            #pragma unroll
            for (int mi = 0; mi < MI; ++mi) {
                const int r = wm * (BM / 2) + mi * 16 + l15;
                af[mi] = *reinterpret_cast<const short8*>(
                    &As[r * 64 + (kb2 ^ ((r & 7) << 3))]);
            }
            #pragma unroll
            for (int ni = 0; ni < NI; ++ni) {
                const int r = wn * (BN / 2) + ni * 16 + l15;
                bfr[ni] = *reinterpret_cast<const short8*>(
                    &Bs[r * 64 + (kb2 ^ ((r & 7) << 3))]);
            }
            #pragma unroll
            for (int mi = 0; mi < MI; ++mi)
                #pragma unroll
                for (int ni = 0; ni < NI; ++ni)
                    acc[mi][ni] = __builtin_amdgcn_mfma_f32_16x16x32_bf16(
                        af[mi], bfr[ni], acc[mi][ni], 0, 0, 0);
        }
    }

    #pragma unroll
    for (int mi = 0; mi < MI; ++mi) {
        #pragma unroll
        for (int ni = 0; ni < NI; ++ni) {
            const int col = nt + wn * (BN / 2) + ni * 16 + l15;
            const int row0 = mt + wm * (BM / 2) + mi * 16 + lg * 4;
            if (MODE == 1) {
                if (col < 512) {
                    #pragma unroll
                    for (int jj = 0; jj < 4; ++jj)
                        qb[(size_t)(row0 + jj) * 512 + col] =
                            f2bf(acc[mi][ni][jj] * QS_);
                } else if (col < 1024) {
                    #pragma unroll
                    for (int jj = 0; jj < 4; ++jj)
                        kb[(size_t)(row0 + jj) * 512 + col - 512] =
                            f2bf(acc[mi][ni][jj]);
                } else {
                    const int dfull = col - 1024;
                    const int hh = dfull >> 6, dd = dfull & 63;
                    const int bb = row0 >> 11, nn = row0 & 2047;
                    u16 o4[4];
                    #pragma unroll
                    for (int jj = 0; jj < 4; ++jj) {
                        o4[jj] = f2bf(acc[mi][ni][jj]);
                        vb[(size_t)(row0 + jj) * 512 + dfull] = o4[jj];
                    }
                    *reinterpret_cast<ushort4*>(
                        &vt[(((size_t)(bb * NH_ + hh)) * HK_ + dd) * N_ + nn]) =
                        make_ushort4(o4[0], o4[1], o4[2], o4[3]);
                }
            } else {
                #pragma unroll
                for (int jj = 0; jj < 4; ++jj) {
                    const size_t row = (size_t)(row0 + jj);
                    float v = acc[mi][ni][jj];
                    v += bias[col];
                    v = fmaxf(v, 0.0f);
                    v += resid[row * Nc + col];
                    Cf[row * Nc + col] = v;
                }
            }
        }
    }
}

// ---------------------------------------------------------------------------
// Flash attention, bf16 MFMA, QBLK=128, 2-phase static dbuf (R10-proven).
// NEW: swapped QK^T — s = mfma(K_tile, Q) computes S^T so each lane holds
// 16 S values of ONE q-row (q = l15) at k = t*16 + lg*4 + jj (jj consecutive).
// P -> LDS becomes 8 packed ds_write_b64 per step (was 32 ds_write_b16),
// into the SAME [q][k] XOR-swizzled layout the PV b128 reads already use
// (read path unchanged). Scalar m_ per lane; rare-path max via shfl_xor(16,32)
// + shfl fac distribution. ones-MFMA row-sum l; setprio (T5).
// ---------------------------------------------------------------------------
__global__ __launch_bounds__(256) void flash_bf16_kernel(
    const u16* __restrict__ Qb, const u16* __restrict__ Kb,
    const u16* __restrict__ Vt, u16* __restrict__ att)
{
    __shared__ u16 Ks0[64 * 64];   // [key][d], XOR-swizzled rows
    __shared__ u16 Ks1[64 * 64];
    __shared__ u16 Vs0[64 * 64];   // [d][key], XOR-swizzled rows
    __shared__ u16 Vs1[64 * 64];
    __shared__ u16 Ps[128 * 64];   // [q][key], XOR-swizzled rows
    const int tid = threadIdx.x;
    const int lane = tid & 63, wave = tid >> 6;
    const int l15 = lane & 15, lg = lane >> 4;
    // grid 512, XCD swizzle (64 blocks per XCD chunk)
    const int lbid = (((int)blockIdx.x & 7) << 6) + ((int)blockIdx.x >> 3);
    const int qt = lbid & 15, h = (lbid >> 4) & 7, b = lbid >> 7;

    short8 aq[2][2];
    #pragma unroll
    for (int qs = 0; qs < 2; ++qs) {
        const int qrow = qt * 128 + qs * 64 + wave * 16 + l15;
        const u16* qp = Qb + ((size_t)(b * N_ + qrow)) * DK_ + h * HK_ + lg * 8;
        aq[qs][0] = *reinterpret_cast<const short8*>(qp);
        aq[qs][1] = *reinterpret_cast<const short8*>(qp + 32);
    }
    short8 ones;
    #pragma unroll
    for (int i = 0; i < 8; ++i) ones[i] = (short)0x3F80;   // bf16 1.0

    const u16* Kbase = Kb + (size_t)b * N_ * DK_ + (size_t)h * HK_;
    const u16* Vbase = Vt + ((size_t)(b * NH_ + h)) * HK_ * N_;
    unsigned long long* Ps64 = reinterpret_cast<unsigned long long*>(Ps);

    f32x4 o[2][5] = {};   // o[qs][4] = row-sum accumulator (l), via ones-MFMA
    float m_[2] = {-1e30f, -1e30f};   // per-lane: running max of q = l15-row

#define STAGE(ktile, KBUF, VBUF) do {                                          \
    _Pragma("unroll")                                                          \
    for (int i_ = 0; i_ < 2; ++i_) {                                           \
        const int ob_ = (wave * 2 + i_) * 1024;                                \
        const int oo_ = ob_ + lane * 16;                                       \
        const int row_ = oo_ >> 7;                                             \
        const int inner_ = (oo_ & 127) ^ ((row_ & 7) << 4);                    \
        gload16((const char*)Kbase +                                           \
                    ((size_t)((ktile) * 64 + row_) * DK_) * 2 + inner_,        \
                (char*)(KBUF) + ob_);                                          \
        gload16((const char*)Vbase +                                           \
                    ((size_t)row_ * N_ + (ktile) * 64) * 2 + inner_,           \
                (char*)(VBUF) + ob_);                                          \
    }                                                                          \
} while (0)

#define FLASH_STEP(KBUF, VBUF) do {                                            \
    f32x4 s[2][4] = {};                                                        \
    __builtin_amdgcn_s_setprio(1);                                             \
    _Pragma("unroll")                                                          \
    for (int ks = 0; ks < 2; ++ks) {                                           \
        const int kb2 = ks * 32 + lg * 8;                                      \
        _Pragma("unroll")                                                      \
        for (int t = 0; t < 4; ++t) {                                          \
            const int r = t * 16 + l15;                                        \
            const short8 bk = *reinterpret_cast<const short8*>(                \
                &(KBUF)[r * 64 + (kb2 ^ ((r & 7) << 3))]);                     \
            s[0][t] = __builtin_amdgcn_mfma_f32_16x16x32_bf16(                 \
                bk, aq[0][ks], s[0][t], 0, 0, 0);                              \
            s[1][t] = __builtin_amdgcn_mfma_f32_16x16x32_bf16(                 \
                bk, aq[1][ks], s[1][t], 0, 0, 0);                              \
        }                                                                      \
    }                                                                          \
    __builtin_amdgcn_s_setprio(0);                                             \
    float rmax[2], cm;                                                         \
    _Pragma("unroll")                                                          \
    for (int qs = 0; qs < 2; ++qs) {                                           \
        float a0 = fmaxf(fmaxf(s[qs][0][0], s[qs][0][1]),                      \
                         fmaxf(s[qs][0][2], s[qs][0][3]));                     \
        float a1 = fmaxf(fmaxf(s[qs][1][0], s[qs][1][1]),                      \
                         fmaxf(s[qs][1][2], s[qs][1][3]));                     \
        float a2 = fmaxf(fmaxf(s[qs][2][0], s[qs][2][1]),                      \
                         fmaxf(s[qs][2][2], s[qs][2][3]));                     \
        float a3 = fmaxf(fmaxf(s[qs][3][0], s[qs][3][1]),                      \
                         fmaxf(s[qs][3][2], s[qs][3][3]));                     \
        rmax[qs] = fmaxf(fmaxf(a0, a1), fmaxf(a2, a3));                        \
    }                                                                          \
    cm = fmaxf(rmax[0] - m_[0], rmax[1] - m_[1]);                              \
    if (__any(cm > 8.0f)) {                                                    \
        _Pragma("unroll")                                                      \
        for (int qs = 0; qs < 2; ++qs) {                                       \
            float rm = rmax[qs];                                               \
            rm = fmaxf(rm, __shfl_xor(rm, 16));                                \
            rm = fmaxf(rm, __shfl_xor(rm, 32));                                \
            const float newm = fmaxf(m_[qs], rm);                              \
            const float fac = exp2f_fast(m_[qs] - newm);                       \
            m_[qs] = newm;                                                     \
            float facq[4];                                                     \
            _Pragma("unroll")                                                  \
            for (int jj = 0; jj < 4; ++jj)                                     \
                facq[jj] = __shfl(fac, lg * 4 + jj);                           \
            _Pragma("unroll")                                                  \
            for (int t = 0; t < 5; ++t)                                        \
                _Pragma("unroll")                                              \
                for (int jj = 0; jj < 4; ++jj)                                 \
                    o[qs][t][jj] *= facq[jj];                                  \
        }                                                                      \
    }                                                                          \
    _Pragma("unroll")                                                          \
    for (int qs = 0; qs < 2; ++qs) {                                           \
        const int prow = qs * 64 + wave * 16 + l15;                            \
        const int pb64 = prow * 16;                                            \
        const int sw1 = (prow & 7) << 1;                                       \
        _Pragma("unroll")                                                      \
        for (int t = 0; t < 4; ++t) {                                          \
            const float p0 = exp2f_fast(s[qs][t][0] - m_[qs]);                 \
            const float p1 = exp2f_fast(s[qs][t][1] - m_[qs]);                 \
            const float p2 = exp2f_fast(s[qs][t][2] - m_[qs]);                 \
            const float p3 = exp2f_fast(s[qs][t][3] - m_[qs]);                 \
            const uint32_t lo = pack2bf(p0, p1);                               \
            const uint32_t hi = pack2bf(p2, p3);                               \
            Ps64[pb64 + ((t * 4 + lg) ^ sw1)] =                                \
                (unsigned long long)lo | ((unsigned long long)hi << 32);       \
        }                                                                      \
    }                                                                          \
    __builtin_amdgcn_s_setprio(1);                                             \
    _Pragma("unroll")                                                          \
    for (int ks = 0; ks < 2; ++ks) {                                           \
        const int kb2 = ks * 32 + lg * 8;                                      \
        const int pr0 = wave * 16 + l15;                                       \
        const int pr1 = 64 + pr0;                                              \
        const short8 ap0 = *reinterpret_cast<const short8*>(                   \
            &Ps[pr0 * 64 + (kb2 ^ ((pr0 & 7) << 3))]);                         \
        const short8 ap1 = *reinterpret_cast<const short8*>(                   \
            &Ps[pr1 * 64 + (kb2 ^ ((pr1 & 7) << 3))]);                         \
        _Pragma("unroll")                                                      \
        for (int t = 0; t < 4; ++t) {                                          \
            const int dr = t * 16 + l15;                                       \
            const short8 bv = *reinterpret_cast<const short8*>(                \
                &(VBUF)[dr * 64 + (kb2 ^ ((dr & 7) << 3))]);                   \
            o[0][t] = __builtin_amdgcn_mfma_f32_16x16x32_bf16(                 \
                ap0, bv, o[0][t], 0, 0, 0);                                    \
            o[1][t] = __builtin_amdgcn_mfma_f32_16x16x32_bf16(                 \
                ap1, bv, o[1][t], 0, 0, 0);                                    \
        }                                                                      \
        o[0][4] = __builtin_amdgcn_mfma_f32_16x16x32_bf16(                     \
            ap0, ones, o[0][4], 0, 0, 0);                                      \
        o[1][4] = __builtin_amdgcn_mfma_f32_16x16x32_bf16(                     \
            ap1, ones, o[1][4], 0, 0, 0);                                      \
    }                                                                          \
    __builtin_amdgcn_s_setprio(0);                                             \
} while (0)

    STAGE(0, Ks0, Vs0);
    __syncthreads();   // buf0 ready

    #pragma unroll 1
    for (int kt = 0; kt < N_ / 64; kt += 2) {
        STAGE(kt + 1, Ks1, Vs1);                       // kt+1 <= 31 always
        FLASH_STEP(Ks0, Vs0);
        __syncthreads();                               // drains prefetch; buf1 ready
        if (kt + 2 < N_ / 64) STAGE(kt + 2, Ks0, Vs0);
        FLASH_STEP(Ks1, Vs1);
        __syncthreads();
    }
#undef STAGE
#undef FLASH_STEP

    #pragma unroll
    for (int qs = 0; qs < 2; ++qs)
        #pragma unroll
        for (int jj = 0; jj < 4; ++jj) {
            const float inv = 1.0f / o[qs][4][jj];
            const size_t row = (size_t)b * N_ + qt * 128 + qs * 64 + wave * 16 + lg * 4 + jj;
            #pragma unroll
            for (int t = 0; t < 4; ++t)
                att[row * (2 * DK_) + h * HK_ + t * 16 + l15] =
                    f2bf_fast(o[qs][t][jj] * inv);
        }
}

// ---------------------------------------------------------------------------
// Feature branch: S_f[kd,qd] = sum_n K[n,kd] * Qs[n,qd]  (MFMA, split over n)
// partials[split][bh][64][64] fp32
// ---------------------------------------------------------------------------
__global__ __launch_bounds__(256) void featS_mfma(
    const u16* __restrict__ Kb, const u16* __restrict__ Qb,
    float* __restrict__ partials)
{
    __shared__ u16 KsT[64 * 64];   // [kd][n], XOR-swizzled
    __shared__ u16 QsT[64 * 64];   // [qd][n], XOR-swizzled
    const int tid = threadIdx.x;
    const int lane = tid & 63, wave = tid >> 6;
    const int l15 = lane & 15, lg = lane >> 4;
    const int ns = blockIdx.x, h = blockIdx.y, b = blockIdx.z;
    const size_t hbase = (size_t)b * N_ * DK_ + (size_t)h * HK_;

    f32x4 acc[4] = {};
    for (int c = 0; c < 4; ++c) {
        const int n0 = ns * 256 + c * 64;
        __syncthreads();
        #pragma unroll
        for (int it = 0; it < 2; ++it) {
            const int idx = tid + it * 256;
            const int n = idx >> 3, d0 = (idx & 7) * 8;
            const u16x8 kv = *reinterpret_cast<const u16x8*>(
                &Kb[hbase + (size_t)(n0 + n) * DK_ + d0]);
            const u16x8 qv = *reinterpret_cast<const u16x8*>(
                &Qb[hbase + (size_t)(n0 + n) * DK_ + d0]);
            #pragma unroll
            for (int j = 0; j < 8; ++j) {
                const int r = d0 + j;
                const int cidx = n ^ ((r & 7) << 3);
                KsT[r * 64 + cidx] = kv[j];
                QsT[r * 64 + cidx] = qv[j];
            }
        }
        __syncthreads();
        #pragma unroll
        for (int ks = 0; ks < 2; ++ks) {
            const int kb2 = ks * 32 + lg * 8;
            const int ar = wave * 16 + l15;
            const short8 aK = *reinterpret_cast<const short8*>(
                &KsT[ar * 64 + (kb2 ^ ((ar & 7) << 3))]);
            #pragma unroll
            for (int ni = 0; ni < 4; ++ni) {
                const int br = ni * 16 + l15;
                const short8 bQ = *reinterpret_cast<const short8*>(
                    &QsT[br * 64 + (kb2 ^ ((br & 7) << 3))]);
                acc[ni] = __builtin_amdgcn_mfma_f32_16x16x32_bf16(aK, bQ, acc[ni], 0, 0, 0);
            }
        }
    }
    const int bh = b * NH_ + h;
    #pragma unroll
    for (int ni = 0; ni < 4; ++ni)
        #pragma unroll
        for (int jj = 0; jj < 4; ++jj) {
            const int row = wave * 16 + lg * 4 + jj;
            partials[(((size_t)ns * 32 + bh) * 64 + row) * 64 + ni * 16 + l15] =
                acc[ni][jj];
        }
}

// sum partials, softmax over qd, write distfT[bh][qd][kd] bf16
__global__ __launch_bounds__(256) void featSM_kernel(
    const float* __restrict__ partials, u16* __restrict__ distfT)
{
    const int bh = blockIdx.x, tid = threadIdx.x;
    const int r = tid >> 2, qq = tid & 3;   // row kd=r, cols qq*16..+15
    float v[16];
    #pragma unroll
    for (int j = 0; j < 16; ++j) v[j] = 0.0f;
    for (int s = 0; s < 8; ++s) {
        const float4* pp = reinterpret_cast<const float4*>(
            &partials[(((size_t)s * 32 + bh) * 64 + r) * 64 + qq * 16]);
        #pragma unroll
        for (int j4 = 0; j4 < 4; ++j4) {
            const float4 a = pp[j4];
            v[j4 * 4 + 0] += a.x; v[j4 * 4 + 1] += a.y;
            v[j4 * 4 + 2] += a.z; v[j4 * 4 + 3] += a.w;
        }
    }
    float m = v[0];
    #pragma unroll
    for (int j = 1; j < 16; ++j) m = fmaxf(m, v[j]);
    m = fmaxf(m, __shfl_xor(m, 1));
    m = fmaxf(m, __shfl_xor(m, 2));
    float sum = 0.0f;
    #pragma unroll
    for (int j = 0; j < 16; ++j) { v[j] = exp2f_fast(v[j] - m); sum += v[j]; }
    sum += __shfl_xor(sum, 1);
    sum += __shfl_xor(sum, 2);
    const float inv = 1.0f / sum;
    #pragma unroll
    for (int j = 0; j < 16; ++j)
        distfT[(size_t)bh * 4096 + (qq * 16 + j) * 64 + r] = f2bf_fast(v[j] * inv);
}

// att_f[n,q] = sum_d V[n,d] * distf[d,q] -> att[:, 512+h*64+q] (MFMA)
__global__ __launch_bounds__(256) void featAV_mfma(
    const u16* __restrict__ V, const u16* __restrict__ distfT,
    u16* __restrict__ att)
{
    __shared__ u16 Bs[64 * 64];   // distfT[q][d], XOR-swizzled
    __shared__ u16 As[64 * 64];   // V rows
    const int tid = threadIdx.x;
    const int lane = tid & 63, wave = tid >> 6;
    const int l15 = lane & 15, lg = lane >> 4;
    const int ns = blockIdx.x, h = blockIdx.y, b = blockIdx.z;
    const int bh = b * NH_ + h;

    #pragma unroll
    for (int it = 0; it < 2; ++it) {
        const int idx = tid + it * 256;
        const int r = idx >> 3, c0 = (idx & 7) * 8;
        const u16x8 dv = *reinterpret_cast<const u16x8*>(
            &distfT[(size_t)bh * 4096 + r * 64 + c0]);
        *reinterpret_cast<u16x8*>(&Bs[r * 64 + (c0 ^ ((r & 7) << 3))]) = dv;
    }

    for (int c = 0; c < 4; ++c) {
        const int n0 = ns * 256 + c * 64;
        __syncthreads();
        #pragma unroll
        for (int i = 0; i < 2; ++i) {
            const int ob = (wave * 2 + i) * 1024;
            const int o_ = ob + lane * 16;
            const int row = o_ >> 7;
            const int inner = (o_ & 127) ^ ((row & 7) << 4);
            gload16((const char*)V + ((size_t)(b * N_ + n0 + row) * DK_ + h * HK_) * 2 + inner,
                    (char*)As + ob);
        }
        __syncthreads();
        f32x4 acc[4] = {};
        #pragma unroll
        for (int ks = 0; ks < 2; ++ks) {
            const int kb2 = ks * 32 + lg * 8;
            const int ar = wave * 16 + l15;
            const short8 av = *reinterpret_cast<const short8*>(
                &As[ar * 64 + (kb2 ^ ((ar & 7) << 3))]);
            #pragma unroll
            for (int ni = 0; ni < 4; ++ni) {
                const int br = ni * 16 + l15;
                const short8 bd = *reinterpret_cast<const short8*>(
                    &Bs[br * 64 + (kb2 ^ ((br & 7) << 3))]);
                acc[ni] = __builtin_amdgcn_mfma_f32_16x16x32_bf16(av, bd, acc[ni], 0, 0, 0);
            }
        }
        #pragma unroll
        for (int ni = 0; ni < 4; ++ni)
            #pragma unroll
            for (int jj = 0; jj < 4; ++jj)
                att[((size_t)b * N_ + n0 + wave * 16 + lg * 4 + jj) * (2 * DK_)
                    + 512 + h * HK_ + ni * 16 + l15] = f2bf_fast(acc[ni][jj]);
    }
}

// ---------------------------------------------------------------------------
__global__ __launch_bounds__(256) void ln_kernel(
    const float* __restrict__ fc, const float* __restrict__ gamma,
    const float* __restrict__ beta, float* __restrict__ out)
{
    __shared__ float red[8];
    const int row = blockIdx.x, tid = threadIdx.x;
    const int c = tid * 2;
    const float2 v = *reinterpret_cast<const float2*>(&fc[(size_t)row * D_ + c]);
    float s = v.x + v.y;
    float sq = v.x * v.x + v.y * v.y;
    #pragma unroll
    for (int off = 32; off >= 1; off >>= 1) {
        s  += __shfl_xor(s, off);
        sq += __shfl_xor(sq, off);
    }
    const int lane = tid & 63, w = tid >> 6;
    if (lane == 0) { red[w] = s; red[4 + w] = sq; }
    __syncthreads();
    s  = red[0] + red[1] + red[2] + red[3];
    sq = red[4] + red[5] + red[6] + red[7];
    const float mu = s * (1.0f / D_);
    const float var = sq * (1.0f / D_) - mu * mu;
    const float rstd = rsqrtf(var + LN_EPS_);
    float2 o;
    o.x = (v.x - mu) * rstd * gamma[c] + beta[c];
    o.y = (v.y - mu) * rstd * gamma[c + 1] + beta[c + 1];
    *reinterpret_cast<float2*>(&out[(size_t)row * D_ + c]) = o;
}

// ---------------------------------------------------------------------------
extern "C" void kernel_launch(void* const* d_in, const int* in_sizes, int n_in,
                              void* d_out, int out_size, void* d_ws, size_t ws_size,
                              hipStream_t stream)
{
    (void)in_sizes; (void)n_in; (void)out_size; (void)ws_size;
    const float* x     = (const float*)d_in[0];
    const float* Wq    = (const float*)d_in[1];
    const float* Wk    = (const float*)d_in[2];
    const float* Wv    = (const float*)d_in[3];
    const float* Wf    = (const float*)d_in[4];
    const float* bf    = (const float*)d_in[5];
    const float* gamma = (const float*)d_in[6];
    const float* beta  = (const float*)d_in[7];
    float* out = (float*)d_out;

    char* w = (char*)d_ws;
    const size_t SZE = (size_t)B_ * N_ * DK_;            // 4,194,304 elems
    u16* xb     = (u16*)w;   w += SZE * 2;
    u16* wqkvT  = (u16*)w;   w += (size_t)1536 * 512 * 2;
    u16* wfT    = (u16*)w;   w += (size_t)512 * 1024 * 2;
    u16* qb     = (u16*)w;   w += SZE * 2;
    u16* kb     = (u16*)w;   w += SZE * 2;
    u16* vb     = (u16*)w;   w += SZE * 2;
    u16* vt     = (u16*)w;   w += SZE * 2;
    u16* attb   = (u16*)w;   w += SZE * 2 * 2;
    float* partials = (float*)w; w += (size_t)8 * 32 * 4096 * 4;   // 4 MB
    u16* distfT = (u16*)w;   w += (size_t)32 * 4096 * 2;
    float* fcout = (float*)w;

    const dim3 blk(256);
    const int M = B_ * N_;

    conv_bf16_kernel<<<dim3((B_ * N_ * D_) / 2048), blk, 0, stream>>>(x, xb, B_ * N_ * D_);
    tc3_kernel<<<dim3(16, 16, 3), blk, 0, stream>>>(Wq, Wk, Wv, wqkvT);
    tcf_kernel<<<dim3(16, 32), blk, 0, stream>>>(Wf, wfT);

    // fused QKV projection: [8192,512] @ [512,1536]; q pre-scaled; v dual-write
    gemm_bf16<128, 128, 1><<<dim3(768), blk, 0, stream>>>(
        xb, wqkvT, nullptr, qb, kb, vb, vt, M, 1536, 512, nullptr, nullptr);

    // QBLK=128 flash, 2-phase pipelined, swapped-QK^T P path: grid 512
    flash_bf16_kernel<<<dim3(512), blk, 0, stream>>>(qb, kb, vt, attb);

    featS_mfma<<<dim3(8, NH_, B_), blk, 0, stream>>>(kb, qb, partials);
    featSM_kernel<<<dim3(32), blk, 0, stream>>>(partials, distfT);
    featAV_mfma<<<dim3(8, NH_, B_), blk, 0, stream>>>(vb, distfT, attb);

    // FC + bias + relu + resid (fp32 out) — reverted to 64x128 / grid 512
    gemm_bf16<64, 128, 2><<<dim3(512), blk, 0, stream>>>(
        attb, wfT, fcout, nullptr, nullptr, nullptr, nullptr, M, D_, 2 * DK_, bf, x);

    ln_kernel<<<dim3(M), blk, 0, stream>>>(fcout, gamma, beta, out);
}